// Round 2
// baseline (11463.728 us; speedup 1.0000x reference)
//
#include <hip/hip_runtime.h>
#include <hip/hip_bf16.h>
#include <hip/hip_fp16.h>

#define T_STEPS 512
#define BATCH   128
#define NID     512
#define DH      512
#define KTOT    1024  // NID + DH
#define NG      2048  // 4*DH

using f16x8 = __attribute__((ext_vector_type(8))) _Float16;
using f32x4 = __attribute__((ext_vector_type(4))) float;

__device__ __forceinline__ float sigmoid_fast(float x) {
    return 1.0f / (1.0f + __expf(-x));
}
__device__ __forceinline__ float tanh_fast(float x) {
    // safe for large |x|: exp(inf)->inf -> 2/inf -> 0 -> 1
    float ax = fabsf(x);
    float e = __expf(2.0f * ax);
    float r = 1.0f - 2.0f / (e + 1.0f);
    return copysignf(r, x);
}

// Arrange W = [Wf; Wr] (1024 x 2048, row-major) into WT[(d*4+g)][k] fp16,
// and bfa[d*4+g] = bf[g*512+d].  One block per output row (2048 blocks x 256 thr).
__global__ void prep_weights(const float* __restrict__ Wf,
                             const float* __restrict__ Wr,
                             const float* __restrict__ bf,
                             _Float16* __restrict__ WT,
                             float* __restrict__ bfa) {
    int orow = blockIdx.x;            // 0..2047 = d*4+g
    int d = orow >> 2;
    int g = orow & 3;
    int col = g * DH + d;             // column index in Wf/Wr (and bf)
    for (int e = 0; e < 4; ++e) {
        int k = (e << 8) + threadIdx.x;   // 0..1023
        float v = (k < NID) ? Wf[(size_t)k * NG + col]
                            : Wr[(size_t)(k - NID) * NG + col];
        WT[(size_t)orow * KTOT + k] = (_Float16)v;
    }
    if (threadIdx.x == 0) bfa[orow] = bf[col];
}

// h0 -> fp16 h buffer, c0 -> f32 c buffer.  64 blocks x 256 thr.
__global__ void prep_state(const float* __restrict__ h0,
                           const float* __restrict__ c0,
                           _Float16* __restrict__ h,
                           float* __restrict__ c) {
    int base = blockIdx.x * 1024 + threadIdx.x;
    for (int e = 0; e < 4; ++e) {
        int i = base + e * 256;
        h[i] = (_Float16)h0[i];
        c[i] = c0[i];
    }
}

// One LSTM timestep, fused GEMM (K=1024) + gates.
// Grid (4, 32): blockIdx.x = batch tile (32 rows), blockIdx.y = d tile (16 d values -> 64 arranged cols).
// 256 threads = 4 waves; wave w: row-tile (w&1), col-tiles 2*(w>>1)+{0,1}.
__global__ __launch_bounds__(256)
void lstm_step(const float* __restrict__ X,        // (T,B,NID)
               const float* __restrict__ imask,    // (T,B)
               const _Float16* __restrict__ WT,    // [2048][1024]
               const float* __restrict__ bfa,      // [2048]
               const _Float16* __restrict__ hin,   // [B][DH] fp16 (read, state t-1)
               _Float16* __restrict__ hout,        // [B][DH] fp16 (write, state t)
               float* __restrict__ c,              // [B][DH] f32 (in/out)
               float* __restrict__ Yout,           // (T,B,DH)
               float* __restrict__ Cout,           // (T,B,DH)
               float* __restrict__ dout,           // (B,DH)
               int t) {
    __shared__ float zs[32][68];   // 64 cols + pad

    const int tid  = threadIdx.x;
    const int lane = tid & 63;
    const int w    = tid >> 6;
    const int l15  = lane & 15;
    const int l4   = lane >> 4;

    const int b0  = blockIdx.x * 32;      // batch tile base
    const int gc0 = blockIdx.y * 64;      // arranged col base (= d0*4)

    const int rt  = w & 1;                // row tile within the 32 rows
    const int ct0 = (w >> 1) * 2;         // first of 2 col tiles

    const int arow = b0 + rt * 16 + l15;  // A-fragment row for this lane
    const float*    xrow = X + ((size_t)t * BATCH + arow) * NID;
    const _Float16* hrow = hin + (size_t)arow * DH;

    const int koff = l4 * 8;              // k offset within a 32-wide K chunk

    // B fragment base pointers (col = gc0 + 16*ct + l15)
    const _Float16* bp0 = WT + (size_t)(gc0 + 16 * ct0 + l15) * KTOT + koff;
    const _Float16* bp1 = WT + (size_t)(gc0 + 16 * (ct0 + 1) + l15) * KTOT + koff;

    f32x4 acc0 = {0.f, 0.f, 0.f, 0.f};
    f32x4 acc1 = {0.f, 0.f, 0.f, 0.f};

    #pragma unroll 4
    for (int k0 = 0; k0 < KTOT; k0 += 32) {
        f16x8 a;
        if (k0 < NID) {
            const float* xp = xrow + k0 + koff;
            f32x4 v0 = *(const f32x4*)xp;
            f32x4 v1 = *(const f32x4*)(xp + 4);
            a[0] = (_Float16)v0[0]; a[1] = (_Float16)v0[1];
            a[2] = (_Float16)v0[2]; a[3] = (_Float16)v0[3];
            a[4] = (_Float16)v1[0]; a[5] = (_Float16)v1[1];
            a[6] = (_Float16)v1[2]; a[7] = (_Float16)v1[3];
        } else {
            a = *(const f16x8*)(hrow + (k0 - NID) + koff);
        }
        f16x8 bf0 = *(const f16x8*)(bp0 + k0);
        f16x8 bf1 = *(const f16x8*)(bp1 + k0);
        acc0 = __builtin_amdgcn_mfma_f32_16x16x32_f16(a, bf0, acc0, 0, 0, 0);
        acc1 = __builtin_amdgcn_mfma_f32_16x16x32_f16(a, bf1, acc1, 0, 0, 0);
    }

    // Scatter accumulators to LDS: D row = (l>>4)*4 + reg, col = l&15 (within tile)
    #pragma unroll
    for (int rg = 0; rg < 4; ++rg) {
        int row = rt * 16 + l4 * 4 + rg;
        zs[row][16 * ct0 + l15]       = acc0[rg];
        zs[row][16 * (ct0 + 1) + l15] = acc1[rg];
    }
    __syncthreads();

    // Gate phase: 32 rows x 16 d = 512 outputs, 2 per thread.
    #pragma unroll
    for (int q = 0; q < 2; ++q) {
        int idx = q * 256 + tid;
        int r  = idx >> 4;      // 0..31
        int dl = idx & 15;      // 0..15
        int b     = b0 + r;
        int dglob = blockIdx.y * 16 + dl;

        f32x4 bb = *(const f32x4*)(bfa + gc0 + dl * 4);
        float z0 = zs[r][dl * 4 + 0] + bb[0];
        float z1 = zs[r][dl * 4 + 1] + bb[1];
        float z2 = zs[r][dl * 4 + 2] + bb[2];
        float z3 = zs[r][dl * 4 + 3] + bb[3];

        float cin = tanh_fast(z0);
        float ig  = sigmoid_fast(z1);
        float fg  = sigmoid_fast(z2);
        float og  = sigmoid_fast(z3);

        float m    = imask[(size_t)t * BATCH + b];
        float cold = c[b * DH + dglob];
        float cnew = m * (cold * fg + cin * ig) + (1.0f - m) * cold;
        float y    = m * (og * tanh_fast(cnew));

        size_t oidx = ((size_t)t * BATCH + b) * DH + dglob;
        Yout[oidx] = y;
        Cout[oidx] = cnew;
        c[b * DH + dglob]    = cnew;
        hout[b * DH + dglob] = (_Float16)y;
        if (t == T_STEPS - 1) dout[b * DH + dglob] = cnew;
    }
}

extern "C" void kernel_launch(void* const* d_in, const int* in_sizes, int n_in,
                              void* d_out, int out_size, void* d_ws, size_t ws_size,
                              hipStream_t stream) {
    const float* X  = (const float*)d_in[0];
    const float* Wf = (const float*)d_in[1];
    const float* Wr = (const float*)d_in[2];
    const float* bf = (const float*)d_in[3];
    const float* im = (const float*)d_in[4];
    const float* h0 = (const float*)d_in[5];
    const float* c0 = (const float*)d_in[6];

    char* ws = (char*)d_ws;
    _Float16* WT   = (_Float16*)ws;                          // 4 MB
    float*    bfa  = (float*)(ws + (4u << 20));              // 8 KB
    _Float16* hb0  = (_Float16*)(ws + (4u << 20) + 8192);    // 128 KB
    _Float16* hb1  = hb0 + BATCH * DH;                       // 128 KB
    float*    cbuf = (float*)(hb1 + BATCH * DH);             // 256 KB

    float* Yout = (float*)d_out;
    float* Cout = Yout + (size_t)T_STEPS * BATCH * DH;
    float* dout = Cout + (size_t)T_STEPS * BATCH * DH;

    hipLaunchKernelGGL(prep_weights, dim3(2048), dim3(256), 0, stream, Wf, Wr, bf, WT, bfa);
    hipLaunchKernelGGL(prep_state,   dim3(64),   dim3(256), 0, stream, h0, c0, hb0, cbuf);

    for (int t = 0; t < T_STEPS; ++t) {
        const _Float16* hin = (t & 1) ? hb1 : hb0;
        _Float16*      hout = (t & 1) ? hb0 : hb1;
        hipLaunchKernelGGL(lstm_step, dim3(4, 32), dim3(256), 0, stream,
                           X, im, WT, bfa, hin, hout, cbuf, Yout, Cout, dout, t);
    }
}